// Round 6
// baseline (193.368 us; speedup 1.0000x reference)
//
#include <hip/hip_runtime.h>

#define B_ 512
#define T_ 512
#define C_ 128
#define L_ 80
#define BLANK_ 127
#define EPS_ 1e-7f
#define LN2_ 0.6931471805599453f

// raw v_log_f32 (base-2); __log2f collides with glibc math.h reserved names.
#define LOG2F(x) __builtin_amdgcn_logf(x)

// DPP cross-lane ops (VALU pipe — DS pipe stays off the critical path).
template <int CTRL> __device__ __forceinline__ int dpp_i(int x) {
  return __builtin_amdgcn_update_dpp(0, x, CTRL, 0xF, 0xF, true);
}
template <int CTRL> __device__ __forceinline__ float dpp_f(float x) {
  return __int_as_float(
      __builtin_amdgcn_update_dpp(0, __float_as_int(x), CTRL, 0xF, 0xF, true));
}
#define DPP_WSHR1 0x138   // wave shift right 1 (lane0 -> 0 via bound_ctrl)
#define DPP_XOR1  0xB1    // quad_perm lane^1
#define DPP_XOR2  0x4E    // quad_perm lane^2
#define DPP_HMIRR 0x141   // row_half_mirror (within 8)
#define DPP_MIRR  0x140   // row_mirror (within 16)

// One wave per batch. Lane i owns extended states 3i..3i+2. Linear-prob DP
// (alpha_new = q*(a0+a1+m*a2)) with per-lane exponent E, rescaled per 8-step
// block. Pipelining: 6-deep global prefetch (block n+7 loaded in body n,
// staged in body n+6; ~1500cyc lead) and double-buffered LDS gathers (block
// n+1's 24 ds_reads issued in body n). Softmax denom factors out of the DP.
__global__ __launch_bounds__(64) void ctc_fused(
    const int* __restrict__ labels,     // [B,L]
    const float* __restrict__ y_pred,   // [B,T,C]
    float* __restrict__ out)            // [B,1]
{
  const int b = blockIdx.x, lane = threadIdx.x;
  const float4* rp = (const float4*)(y_pred + (size_t)b * T_ * C_);
  __shared__ float ring[2 * 8 * C_];    // 2 banks x 8 rows x 128 floats

  const int rgrp = lane >> 3, j16 = lane & 7;
  const bool evenLane = ((lane & 1) == 0);

  auto labAt = [&](int k) -> int {
    return (k >= 0 && k < L_) ? labels[b * L_ + k] : BLANK_;
  };
  // Per-state gather symbols (q_i = p[x_i]+eps) and skip masks — no selects
  // left in the DP step.
  int x0, x1, x2; float m0, m1, m2;
  if (evenLane) {                        // states: blank / label k1 / blank
    const int k1 = (3 * lane) >> 1;
    const int e = labAt(k1);
    x0 = BLANK_; x1 = e; x2 = BLANK_;
    m0 = 0.f; m2 = 0.f;
    m1 = ((k1 < L_) && (k1 == 0 || e != labAt(k1 - 1))) ? 1.f : 0.f;
  } else {                               // states: label k0 / blank / label k2
    const int k0 = (3 * lane - 1) >> 1, k2 = k0 + 1;
    const int ea = labAt(k0), eb = labAt(k2);
    x0 = ea; x1 = BLANK_; x2 = eb;
    m0 = ((k0 < L_) && (k0 == 0 || ea != labAt(k0 - 1))) ? 1.f : 0.f;
    m1 = 0.f;
    m2 = ((k2 < L_) && (eb != ea)) ? 1.f : 0.f;
  }

  float Sacc = 0.f;
  float A0, A1, A2; int E = 0;

  auto gload = [&](float4 (&S)[4], int blk) {
    int row = blk * 8 + rgrp; if (row > T_ - 1) row = T_ - 1;
    const float4* src = rp + row * 32 + 4 * j16;
    #pragma unroll
    for (int k = 0; k < 4; ++k) S[k] = src[k];
  };
  // eps-add, stage to ring bank, fused row-sum (DPP reduce) + log2
  auto prep = [&](float4 (&Sw)[4], int bankDst) {
    #pragma unroll
    for (int k = 0; k < 4; ++k) {
      Sw[k].x += EPS_; Sw[k].y += EPS_; Sw[k].z += EPS_; Sw[k].w += EPS_;
    }
    float4* wd = (float4*)(ring + bankDst * 1024 + rgrp * C_ + 16 * j16);
    #pragma unroll
    for (int k = 0; k < 4; ++k) wd[k] = Sw[k];
    float s = 0.f;
    #pragma unroll
    for (int k = 0; k < 4; ++k) s += (Sw[k].x + Sw[k].y) + (Sw[k].z + Sw[k].w);
    s += dpp_f<DPP_XOR1>(s);
    s += dpp_f<DPP_XOR2>(s);
    s += dpp_f<DPP_HMIRR>(s);
    Sacc += LOG2F(s);                   // 8x redundant per row; /8 at the end
  };
  auto gath = [&](float (&q0)[8], float (&q1)[8], float (&q2)[8], int bank) {
    const float* rb = ring + bank * 1024;
    #pragma unroll
    for (int j = 0; j < 8; ++j) {
      q0[j] = rb[j * C_ + x0];
      q1[j] = rb[j * C_ + x1];
      q2[j] = rb[j * C_ + x2];
    }
  };
  auto dp8 = [&](float (&q0)[8], float (&q1)[8], float (&q2)[8]) {
    const int EL = dpp_i<DPP_WSHR1>(E);
    const int d = E - EL;               // block-constant reconcile shift
    #pragma unroll
    for (int j = 0; j < 8; ++j) {
      const float p1 = dpp_f<DPP_WSHR1>(A1);   // left A1 (state 3i-2)
      const float p2 = dpp_f<DPP_WSHR1>(A2);   // left A2 (state 3i-1)
      const float p1p = ldexpf(p1, d);
      const float p2p = ldexpf(p2, d);
      const float t0 = q0[j] * fmaf(m0, p1p, A0 + p2p);
      const float t1 = q1[j] * fmaf(m1, p2p, A1 + A0);
      const float t2 = q2[j] * fmaf(m2, A0, A2 + A1);
      A0 = t0; A1 = t1; A2 = t2;
    }
    // per-lane rescale: fold lane max exponent into E
    const float mx = fmaxf(fmaxf(A0, A1), A2);
    int ee = (int)((__float_as_uint(mx) >> 23) & 255u) - 127;
    const bool z = (mx == 0.f);
    ee = z ? 0 : ee;
    A0 = ldexpf(A0, -ee); A1 = ldexpf(A1, -ee); A2 = ldexpf(A2, -ee);
    E = z ? EL : (E - ee);              // virgin lanes track left neighbor
  };

  // ---- prologue: sets 0..5 <- blocks 0..5; stage+gather block 0; S0 <- 6 ----
  float4 S0[4], S1[4], S2[4], S3[4], S4[4], S5[4];
  gload(S0, 0); gload(S1, 1); gload(S2, 2);
  gload(S3, 3); gload(S4, 4); gload(S5, 5);
  float g0[2][8], g1[2][8], g2[2][8];
  prep(S0, 0);
  gath(g0[0], g1[0], g2[0], 0);
  gload(S0, 6);
  // virtual init: one DP step from (A0=1@lane0) yields exact alpha(t=0)
  A0 = (lane == 0) ? 1.f : 0.f; A1 = 0.f; A2 = 0.f;

  // body(n): stage block n+1 (bank (n+1)&1), issue its gathers (consumed next
  // body), reload freed set with block n+7, then run 8 DP steps of block n
  // on gathers issued last body.
  auto body = [&](int n, float4 (&Sst)[4],
                  float (&c0)[8], float (&c1)[8], float (&c2)[8],
                  float (&n0)[8], float (&n1)[8], float (&n2)[8],
                  bool doStage) {
    if (doStage) {
      const int bk = (n + 1) & 1;
      prep(Sst, bk);
      gath(n0, n1, n2, bk);
      gload(Sst, n + 7);
    }
    dp8(c0, c1, c2);
  };

  #define BODY(N, SET, CUR, NXT, ST) \
    body((N), SET, g0[CUR], g1[CUR], g2[CUR], g0[NXT], g1[NXT], g2[NXT], ST)

  for (int nn = 0; nn < 54; nn += 6) {
    BODY(nn + 0, S1, 0, 1, true);
    BODY(nn + 1, S2, 1, 0, true);
    BODY(nn + 2, S3, 0, 1, true);
    BODY(nn + 3, S4, 1, 0, true);
    BODY(nn + 4, S5, 0, 1, true);
    BODY(nn + 5, S0, 1, 0, true);
  }
  BODY(54, S1, 0, 1, true);
  BODY(55, S2, 1, 0, true);
  BODY(56, S3, 0, 1, true);
  BODY(57, S4, 1, 0, true);
  BODY(58, S5, 0, 1, true);
  BODY(59, S0, 1, 0, true);
  BODY(60, S1, 0, 1, true);
  BODY(61, S2, 1, 0, true);
  BODY(62, S3, 0, 1, true);
  BODY(63, S4, 1, 0, false);            // last block: no staging/prefetch

  // ---- denominator total (each row counted 8x -> *0.125) ----
  float s = Sacc;
  s += dpp_f<DPP_XOR1>(s);
  s += dpp_f<DPP_XOR2>(s);
  s += dpp_f<DPP_HMIRR>(s);
  s += dpp_f<DPP_MIRR>(s);
  s += __shfl_xor(s, 16, 64);
  s += __shfl_xor(s, 32, 64);
  const float Stot = s * 0.125f;

  // loss = ln2 * (S - (log2(A159+A160) - E));  lane 53: A0=s159, A1=s160
  if (lane == 53) {
    const float lse2 = LOG2F(A0 + A1) - (float)E;
    out[b] = LN2_ * (Stot - lse2);
  }
}

extern "C" void kernel_launch(void* const* d_in, const int* in_sizes, int n_in,
                              void* d_out, int out_size, void* d_ws, size_t ws_size,
                              hipStream_t stream) {
  const int*   labels = (const int*)d_in[0];    // y_true [B,L]
  const float* y_pred = (const float*)d_in[1];  // y_pred [B,T,C]
  float*       out    = (float*)d_out;          // [B,1]
  ctc_fused<<<dim3(B_), dim3(64), 0, stream>>>(labels, y_pred, out);
}